// Round 11
// baseline (118.109 us; speedup 1.0000x reference)
//
#include <hip/hip_runtime.h>
#include <hip/hip_bf16.h>

typedef unsigned int u32;
typedef __attribute__((ext_vector_type(8))) _Float16 f16x8;
typedef __attribute__((ext_vector_type(4))) float f32x4;

#define GMIN_ 0.01f
#define GMAX_ 10.0f
#define LOG2E_ 1.4426950408889634f

// tanh(y) with pre-scaled arg: given y2l = 2*y*log2(e),
// tanh(y) = 1 - 2/(exp2(y2l)+1).
__device__ __forceinline__ float tanh_exp2(float y2l) {
    float e = __builtin_amdgcn_exp2f(y2l);
    float r = __builtin_amdgcn_rcpf(e + 1.0f);
    return fmaf(-2.0f, r, 1.0f);
}

__device__ __forceinline__ float clamp_thresh(float tt) {
    tt = fminf(fmaxf(tt, -GMAX_), GMAX_);
    return (fabsf(tt) < GMIN_) ? 0.f : tt;
}

// ---------------------------------------------------------------------------
// Fully fused pLayer: one kernel, no workspace.
// Block = 128 rows x 64 cols, 4 waves over m (wave 32x64). Grid = 1024
// (256 mblk x 4 nblk) = 4 blocks/CU.
// Phase 0: block computes its 64 columns' |theta| norm sums (258 rows) and
//          bias (row 256 folded with ptanh(1,eta_inv)) into LDS.
// Chunks r=0..3 (K=128 f16 each): W-pack computed straight from L2-hot theta
//          into double-buffered, XOR-swizzled B LDS (ds_write_b128);
//          A direct from global with 2-deep register prefetch and on-the-fly
//          {f16(a), f16(ptanh_inv(a))} interleave; 16x16x32 f16 MFMA.
// ---------------------------------------------------------------------------
__global__ __launch_bounds__(256, 4) void plax_fused(
    const float* __restrict__ A, const float* __restrict__ theta,
    const float* __restrict__ eta_act, const float* __restrict__ eta_inv,
    float* __restrict__ out)
{
    __shared__ __align__(16) char Bs[2][16384];  // [buf][col 0..63][slot 0..15][16B]
    __shared__ float psum[4][64];
    __shared__ float sinv[64];
    __shared__ float sbias[64];

    const int t    = threadIdx.x;
    const int bid  = blockIdx.x;
    const int swz  = ((bid & 7) << 7) | (bid >> 3);   // XCD-bijective, 1024 = 8*128
    const int mblk = swz >> 2;       // 0..255
    const int nblk = swz & 3;        // 0..3
    const int lane = t & 63, wave = t >> 6;
    const int lr   = lane & 15, lg = lane >> 4;
    const int cl   = t & 63;         // column-local (staging/norm role)
    const int sg   = t >> 6;         // slot-group == wave id

    const float ei0 = eta_inv[0], ei1 = eta_inv[1], ei2 = eta_inv[2], ei3 = eta_inv[3];
    const float k2i = 2.0f * ei3 * LOG2E_;
    const float c2i = 2.0f * ei2 * ei3 * LOG2E_;

    const int row0 = mblk * 128 + wave * 32;
    const int col0 = nblk * 64;

    const float* ap = A + (size_t)(row0 + lr) * 256 + lg * 4;
    const float* thc = theta + col0 + cl;      // this thread's theta column

    f32x4 acc[2][4] = {};
    float4 aq[3][2];   // 3-slot / 2-deep A prefetch, all indices compile-time

#define LDA(it_) do {                                                \
        aq[(it_) % 3][0] = *(const float4*)(ap + (it_) * 16);        \
        aq[(it_) % 3][1] = *(const float4*)(ap + 4096 + (it_) * 16); \
    } while (0)

    // theta rows for chunk r_, this thread: k = r_*64 + sg*16 + q, q=0..15
    float tth[16];
#define LOAD_TH(r_) do {                                             \
        _Pragma("unroll")                                            \
        for (int q_ = 0; q_ < 16; ++q_)                              \
            tth[q_] = thc[((r_) * 64 + sg * 16 + q_) * 256];         \
    } while (0)

    // pack tth -> 4 x f16x8, ds_write to Bs[bb_] (XOR slot swizzle)
#define PACK_WRITE(bb_, inv_) do {                                   \
        _Pragma("unroll")                                            \
        for (int si_ = 0; si_ < 4; ++si_) {                          \
            f16x8 h_;                                                \
            _Pragma("unroll")                                        \
            for (int e_ = 0; e_ < 4; ++e_) {                         \
                const float tt_ = clamp_thresh(tth[si_ * 4 + e_]);   \
                const float w_  = fabsf(tt_) * (inv_);               \
                const float wp_ = (tt_ >= 0.f) ? w_ : 0.f;           \
                h_[2 * e_]     = (_Float16)wp_;                      \
                h_[2 * e_ + 1] = (_Float16)(w_ - wp_);               \
            }                                                        \
            *(f16x8*)((char*)Bs + (bb_) * 16384 + cl * 256           \
                      + (((sg * 4 + si_) ^ (cl & 15)) * 16)) = h_;   \
        }                                                            \
    } while (0)

    // ---- phase 0: open A pipeline, column norms, chunk-0 theta loads ----
    LDA(0); LDA(1);

    float part = 0.f;
    for (int k = sg; k < 258; k += 4)
        part += fabsf(clamp_thresh(thc[k * 256]));
    psum[sg][cl] = part;

    LOAD_TH(0);                       // chunk-0 rows; no dependence on sums
    __syncthreads();
    if (t < 64) {
        const float s  = psum[0][t] + psum[1][t] + psum[2][t] + psum[3][t];
        const float iv = 1.0f / s;
        sinv[t] = iv;
        const float t6 = clamp_thresh(theta[256 * 256 + col0 + t]);
        const float w6 = fabsf(t6) * iv;
        const float wp = (t6 >= 0.f) ? w6 : 0.f;
        const float a1 = ei0 + ei1 * tanh_exp2((1.0f - ei2) * ei3 * 2.0f * LOG2E_);
        sbias[t] = wp + a1 * (w6 - wp);
    }
    __syncthreads();
    const float inv = sinv[cl];

    // publish chunk 0
    PACK_WRITE(0, inv);
    asm volatile("s_waitcnt lgkmcnt(0)" ::: "memory");
    __builtin_amdgcn_sched_barrier(0);
    __builtin_amdgcn_s_barrier();

#pragma unroll
    for (int r = 0; r < 4; ++r) {
        if (r < 3) LOAD_TH(r + 1);    // issue early; lands during compute

        const char* buf = (const char*)Bs + (r & 1) * 16384;
#pragma unroll
        for (int j = 0; j < 4; ++j) {
            const int it = r * 4 + j;
            if (it + 2 < 16) LDA(it + 2);          // 2-deep A prefetch

            const float4* acur = aq[it % 3];
            f16x8 af[2];
#pragma unroll
            for (int m = 0; m < 2; ++m) {
                const float4 v = acur[m];
                f16x8 h;
                h[0] = (_Float16)v.x;
                h[1] = (_Float16)fmaf(ei1, tanh_exp2(fmaf(v.x, k2i, -c2i)), ei0);
                h[2] = (_Float16)v.y;
                h[3] = (_Float16)fmaf(ei1, tanh_exp2(fmaf(v.y, k2i, -c2i)), ei0);
                h[4] = (_Float16)v.z;
                h[5] = (_Float16)fmaf(ei1, tanh_exp2(fmaf(v.z, k2i, -c2i)), ei0);
                h[6] = (_Float16)v.w;
                h[7] = (_Float16)fmaf(ei1, tanh_exp2(fmaf(v.w, k2i, -c2i)), ei0);
                af[m] = h;
            }

            f16x8 bf[4];
#pragma unroll
            for (int n = 0; n < 4; ++n) {
                const int rr   = n * 16 + lr;
                const int phys = (j * 4 + lg) ^ lr;     // logical ^ (col&15)
                bf[n] = *(const f16x8*)(buf + rr * 256 + phys * 16);
            }

#pragma unroll
            for (int m = 0; m < 2; ++m)
#pragma unroll
                for (int n = 0; n < 4; ++n)
                    acc[m][n] = __builtin_amdgcn_mfma_f32_16x16x32_f16(
                        af[m], bf[n], acc[m][n], 0, 0, 0);
        }

        if (r < 3) {
            __builtin_amdgcn_s_barrier();           // done reading Bs[(r+1)&1]
            PACK_WRITE((r + 1) & 1, inv);           // tth landed during compute
            asm volatile("s_waitcnt lgkmcnt(0)" ::: "memory");
            __builtin_amdgcn_sched_barrier(0);
            __builtin_amdgcn_s_barrier();           // writes visible
        }
    }
#undef LDA
#undef LOAD_TH
#undef PACK_WRITE

    // ---- epilogue: z = acc + bias ; out = ptanh_act(z) ----
    const float ea0 = eta_act[0], ea1 = eta_act[1];
    const float k2a = 2.0f * eta_act[3] * LOG2E_;
    const float c2a = 2.0f * eta_act[2] * eta_act[3] * LOG2E_;

    float bc[4];
#pragma unroll
    for (int n = 0; n < 4; ++n) bc[n] = sbias[n * 16 + lr];

#pragma unroll
    for (int m = 0; m < 2; ++m) {
        const int rgb = row0 + m * 16 + lg * 4;
#pragma unroll
        for (int n = 0; n < 4; ++n) {
            const int cg = col0 + n * 16 + lr;
#pragma unroll
            for (int j = 0; j < 4; ++j) {
                const float z = acc[m][n][j] + bc[n];
                out[(size_t)(rgb + j) * 256 + cg] =
                    fmaf(ea1, tanh_exp2(fmaf(z, k2a, -c2a)), ea0);
            }
        }
    }
}

// ---------------------------------------------------------------------------
extern "C" void kernel_launch(void* const* d_in, const int* in_sizes, int n_in,
                              void* d_out, int out_size, void* d_ws, size_t ws_size,
                              hipStream_t stream) {
    (void)in_sizes; (void)n_in; (void)out_size; (void)d_ws; (void)ws_size;
    const float* a       = (const float*)d_in[0];
    const float* theta   = (const float*)d_in[1];
    const float* eta_act = (const float*)d_in[2];
    const float* eta_inv = (const float*)d_in[3];
    float* out = (float*)d_out;

    plax_fused<<<1024, 256, 0, stream>>>(a, theta, eta_act, eta_inv, out);
}